// Round 11
// baseline (36.605 us; speedup 1.0000x reference)
//
#include <hip/hip_runtime.h>

// D-FINE post-processor, SINGLE fused kernel: one block per batch (256 x 1024).
//   Filter: asm-pinned load pipeline. 16 global_load_dwordx4 issued
//     back-to-back via inline asm (compiler cannot jam/serialize them), then
//     counted s_waitcnt vmcnt(8)/vmcnt(4)/vmcnt(0) with sched_barrier(0)
//     fences: consume phase A while phase B is still in flight, issue phase C
//     before consuming B. Hits (logit > THR) compact into LDS cand[] via an
//     LDS counter. {x > THR} is a prefix of the descending order, so if
//     K <= n <= CAPL the top-K is provably contained.
//   Select: rank-based (count-of-greater over packed (key<<32)|~idx keys =
//     exact jax.lax.top_k tie semantics, broadcast LDS reads), scatter-emit
//     by rank.
//   Fallback: exact in-kernel 4096-bin histogram selection if the bound check
//     fails (any input distribution stays correct).
// Output (float32): labels [B*K] | boxes [B*K*4] | scores [B*K]

typedef float f32x4 __attribute__((ext_vector_type(4)));

constexpr int   NT    = 1024;
constexpr int   NBINS = 4096;
constexpr int   CAPL  = 4096;   // LDS candidate capacity
constexpr float THR   = 2.4f;   // static pre-filter (fallback makes it safe)

__device__ __forceinline__ unsigned f2key(float f) {
    unsigned u = __float_as_uint(f);
    return (u & 0x80000000u) ? ~u : (u | 0x80000000u);
}
__device__ __forceinline__ float key2f(unsigned k) {
    unsigned u = (k & 0x80000000u) ? (k & 0x7FFFFFFFu) : ~k;
    return __uint_as_float(u);
}
__device__ __forceinline__ unsigned long long packkv(unsigned key, unsigned idx) {
    return ((unsigned long long)key << 32) | (unsigned long long)(0xFFFFFFFFu - idx);
}

// asm-pinned 16B load: compiler treats it as opaque -> cannot reorder
// relative to other asm volatiles, cannot insert its own waitcnt.
__device__ __forceinline__ f32x4 gload4(const f32x4* p) {
    f32x4 r;
    asm volatile("global_load_dwordx4 %0, %1, off" : "=v"(r) : "v"(p));
    return r;
}

__device__ __forceinline__ void consume1(
    float x, unsigned idx, unsigned* lcnt, unsigned long long* cand)
{
    if (x > THR) {
        unsigned p = atomicAdd(lcnt, 1u);
        if (p < (unsigned)CAPL) cand[p] = packkv(f2key(x), idx);
    }
}
__device__ __forceinline__ void consume4(
    f32x4 v, int i4, int N4, unsigned* lcnt, unsigned long long* cand)
{
    if (i4 < N4) {
        float mx = fmaxf(fmaxf(v[0], v[1]), fmaxf(v[2], v[3]));
        if (mx > THR) {
            unsigned bi = (unsigned)(4 * i4);
            consume1(v[0], bi + 0, lcnt, cand);
            consume1(v[1], bi + 1, lcnt, cand);
            consume1(v[2], bi + 2, lcnt, cand);
            consume1(v[3], bi + 3, lcnt, cand);
        }
    }
}

__global__ __launch_bounds__(NT) void dfine_fused_kernel(
    const float* __restrict__ logits,   // [B, Q*C]
    const float* __restrict__ pboxes,   // [B, Q, 4]  (cx, cy, w, h)
    const float* __restrict__ sizes,    // [B, 2]
    float* __restrict__ out,            // labels | boxes | scores
    int B, int Q, int C, int K)
{
    const int b   = blockIdx.x;
    const int tid = threadIdx.x;
    const int N   = Q * C;
    const int N4  = N >> 2;             // N divisible by 4 (C=80)
    const f32x4* __restrict__ base4 = reinterpret_cast<const f32x4*>(logits + (long long)b * N);

    __shared__ unsigned long long cand[CAPL];   // 32 KB
    __shared__ unsigned hist[NBINS];            // 16 KB (fallback only)
    __shared__ unsigned partial[NT];            //  4 KB (fallback only)
    __shared__ unsigned lcnt;
    __shared__ unsigned candCount;
    __shared__ unsigned threshBin;

    if (tid == 0) lcnt = 0u;
    __syncthreads();

    // ---- filter: asm-pinned 3-phase pipeline (A=8, B=8, C=4 f32x4/thread) ----
    {
        f32x4 va[8], vb[8], vc[4];
        // issue A + B back-to-back: 16 loads (16 KB) in flight per wave
        #pragma unroll
        for (int j = 0; j < 8; ++j) {
            int i4 = j * NT + tid;
            va[j] = gload4(base4 + ((i4 < N4) ? i4 : (N4 - 1)));
        }
        #pragma unroll
        for (int j = 0; j < 8; ++j) {
            int i4 = (8 + j) * NT + tid;
            vb[j] = gload4(base4 + ((i4 < N4) ? i4 : (N4 - 1)));
        }
        asm volatile("s_waitcnt vmcnt(8)");          // A retired (in-order)
        __builtin_amdgcn_sched_barrier(0);
        #pragma unroll
        for (int j = 0; j < 8; ++j)
            consume4(va[j], j * NT + tid, N4, &lcnt, cand);
        // issue C while B still in flight
        #pragma unroll
        for (int j = 0; j < 4; ++j) {
            int i4 = (16 + j) * NT + tid;
            vc[j] = gload4(base4 + ((i4 < N4) ? i4 : (N4 - 1)));
        }
        asm volatile("s_waitcnt vmcnt(4)");          // B retired
        __builtin_amdgcn_sched_barrier(0);
        #pragma unroll
        for (int j = 0; j < 8; ++j)
            consume4(vb[j], (8 + j) * NT + tid, N4, &lcnt, cand);
        asm volatile("s_waitcnt vmcnt(0)");          // C retired
        __builtin_amdgcn_sched_barrier(0);
        #pragma unroll
        for (int j = 0; j < 4; ++j)
            consume4(vc[j], (16 + j) * NT + tid, N4, &lcnt, cand);
        __builtin_amdgcn_sched_barrier(0);           // seal the pinned region
    }
    // generic tail for hypothetical larger shapes (no-op at N4 = 20000)
    for (int i4 = 20 * NT + tid; i4 < N4; i4 += NT) {
        const float4 x = *reinterpret_cast<const float4*>(base4 + i4);
        f32x4 v; v[0] = x.x; v[1] = x.y; v[2] = x.z; v[3] = x.w;
        consume4(v, i4, N4, &lcnt, cand);
    }
    __syncthreads();

    int n;
    const unsigned tot = lcnt;
    if (tot >= (unsigned)K && tot <= (unsigned)CAPL) {
        n = (int)tot;                               // hot path: cand[] already in LDS
    } else {
        // ---- fallback: exact histogram selection over the full batch ----
        const float* __restrict__ lg = logits + (long long)b * N;
        for (int i = tid; i < NBINS; i += NT) hist[i] = 0u;
        if (tid == 0) candCount = 0u;
        __syncthreads();
        for (int i = tid; i < N; i += NT)
            atomicAdd(&hist[f2key(lg[i]) >> 20], 1u);
        __syncthreads();
        {
            const int BPT = NBINS / NT;
            unsigned s = 0;
            #pragma unroll
            for (int m = 0; m < BPT; ++m) s += hist[tid * BPT + m];
            partial[tid] = s;
        }
        __syncthreads();
        if (tid < 64) {
            const int PPG = NT / 64;
            unsigned gs = 0;
            #pragma unroll
            for (int m = 0; m < PPG; ++m) gs += partial[tid * PPG + m];
            unsigned pre = gs;
            #pragma unroll
            for (int off = 1; off < 64; off <<= 1) {
                unsigned t = __shfl_up(pre, off);
                if (tid >= off) pre += t;
            }
            unsigned total = __shfl(pre, 63);
            unsigned suf   = total - (pre - gs);
            unsigned long long m1 = __ballot(suf >= (unsigned)K);
            int g = 63 - __clzll(m1);
            unsigned above = total - __shfl(pre, g);
            unsigned hv = hist[g * 64 + tid];
            unsigned pre2 = hv;
            #pragma unroll
            for (int off = 1; off < 64; off <<= 1) {
                unsigned t = __shfl_up(pre2, off);
                if (tid >= off) pre2 += t;
            }
            unsigned total2 = __shfl(pre2, 63);
            unsigned suf2   = above + total2 - (pre2 - hv);
            unsigned long long m2 = __ballot(suf2 >= (unsigned)K);
            int l2 = 63 - __clzll(m2);
            if (tid == 0) threshBin = (unsigned)(g * 64 + l2);
        }
        __syncthreads();
        const unsigned tb = threshBin;
        for (int i = tid; i < N; i += NT) {
            unsigned k = f2key(lg[i]);
            if ((k >> 20) >= tb) {
                unsigned p = atomicAdd(&candCount, 1u);
                if (p < (unsigned)CAPL) cand[p] = packkv(k, (unsigned)i);
            }
        }
        __syncthreads();
        n = (int)min(candCount, (unsigned)CAPL);
    }

    // ---- rank-based selection + emit ----
    const int BK = B * K;
    float* __restrict__ out_labels = out;
    float* __restrict__ out_boxes  = out + BK;
    float* __restrict__ out_scores = out + (long long)BK * 5;
    const float s0 = sizes[2 * b];
    const float s1 = sizes[2 * b + 1];

    for (int t = tid; t < n; t += NT) {
        unsigned long long my = cand[t];
        int r = 0;
        for (int j = 0; j < n; ++j) r += (cand[j] > my);   // packed keys unique
        if (r < K) {
            unsigned key = (unsigned)(my >> 32);
            unsigned idx = 0xFFFFFFFFu - (unsigned)(my & 0xFFFFFFFFull);
            float logit = key2f(key);
            float score = 1.0f / (1.0f + expf(-logit));
            int label = (int)(idx % (unsigned)C);
            int q     = (int)(idx / (unsigned)C);
            float4 bp = *reinterpret_cast<const float4*>(pboxes + ((long long)b * Q + q) * 4);
            int o = b * K + r;
            out_labels[o] = (float)label;
            out_scores[o] = score;
            float4 bb;
            bb.x = (bp.x - 0.5f * bp.z) * s0;
            bb.y = (bp.y - 0.5f * bp.w) * s1;
            bb.z = (bp.x + 0.5f * bp.z) * s0;
            bb.w = (bp.y + 0.5f * bp.w) * s1;
            *reinterpret_cast<float4*>(out_boxes + 4LL * o) = bb;
        }
    }
}

extern "C" void kernel_launch(void* const* d_in, const int* in_sizes, int n_in,
                              void* d_out, int out_size, void* d_ws, size_t ws_size,
                              hipStream_t stream) {
    const float* logits = (const float*)d_in[0];
    const float* pboxes = (const float*)d_in[1];
    const float* sizes  = (const float*)d_in[2];

    const int B = in_sizes[2] / 2;                 // 256
    const int Q = in_sizes[1] / (4 * B);           // 1000
    const int C = in_sizes[0] / (B * Q);           // 80
    const int K = out_size / (6 * B);              // 300

    dfine_fused_kernel<<<B, NT, 0, stream>>>(
        logits, pboxes, sizes, (float*)d_out, B, Q, C, K);
}